// Round 15
// baseline (332.320 us; speedup 1.0000x reference)
//
#include <hip/hip_runtime.h>
#include <hip/hip_bf16.h>

#define H 4096
#define NEXP 256
#define TOPK 8
#define NGROUP 8
#define TOPKG 4
#define ROUTED_SCALING 2.5f
#define WSCALE 1024.0f
#define INV_WSCALE (1.0f / 1024.0f)

#define PART_OFF ((size_t)4 * 1024 * 1024)
#define WS_NEED  (PART_OFF + (size_t)2048 * 16384)   // 4MB wfrags + 32MB partials

typedef __attribute__((ext_vector_type(8)))  _Float16 f16x8;
typedef __attribute__((ext_vector_type(16))) float    f32x16;
typedef __attribute__((ext_vector_type(4)))  float    f32x4;

// ============================================================================
// Pre-kernel: split W*1024 into 2 fp16 levels, 32x32x16 B-fragment order,
// levels interleaved per ks: addr = etile*524288 + (ks*2+lvl)*1024 + l*16.
// ============================================================================
__global__ __launch_bounds__(256) void wsplit_kernel(
    const float* __restrict__ W, char* __restrict__ ws)
{
    const int t  = blockIdx.x * 256 + threadIdx.x;
    const int l  = t & 63;
    const int ks = (t >> 6) & 255;
    const int eg = t >> 14;
    const int expert = eg * 32 + (l & 31);
    const int k0 = ks * 16 + (l >> 5) * 8;
    const float* src = W + (size_t)expert * H + k0;
    float xf[8];
    *(float4*)&xf[0] = *(const float4*)(src);
    *(float4*)&xf[4] = *(const float4*)(src + 4);
    union { _Float16 h[8]; int4 q; } o1, o2;
#pragma unroll
    for (int j = 0; j < 8; ++j) {
        const float x = xf[j] * WSCALE;
        const _Float16 h1 = (_Float16)x;
        o1.h[j] = h1;
        o2.h[j] = (_Float16)(x - (float)h1);
    }
    const size_t off = ((size_t)((eg * 256 + ks) * 2)) * 1024 + (size_t)l * 16;
    *(int4*)(ws + off)        = o1.q;
    *(int4*)(ws + off + 1024) = o2.q;
}

// ============================================================================
// Kernel A (v9): 2048 blocks x 256 thr (4 waves), target 3 blocks/CU
// (12 waves/CU). Block (mt=bid>>2, kb=(bid&3)>>1, eh=bid&1):
// 32 tokens x 128 experts (etiles eh*4..eh*4+3) x half-K.
// (kb,eh) constant per XCD (XCD=bid%8) -> per-XCD W set = 1 MB.
// ROUND-14 LESSON: v8's (256,3) silently failed (180 unified regs > 170
// -> 8 waves/CU). v9 budget: acc 48 + rb 64 (8-DEEP ring, covers ~1200cyc
// lookahead >= L3 latency - the suspected v6 stall) + x 16 + temps ~35
// ~= 165 <= 170. Wave = 1 etile (3 MFMA/step, 2 B-loads/step).
// rb[i] consumed at step i, reloaded immediately for next slice's step i.
// T5 setprio around MFMA cluster (3 blocks/CU at independent phases).
// Numerics (proven r5..r12): x1w1 -> acc_hi drained to fp32 tot per slice;
// x1w2+x2w1 chained in acc_rest (2^-11 scale).
// LDS 32KB: XA[2buf][2lvl][8slot][64l]x16B; staging thread = slots w, w+4.
// ============================================================================
__global__ __launch_bounds__(256, 3) void moe_partial_v9(
    const float* __restrict__ X, char* ws, int T)
{
    __shared__ __align__(16) char SM[32768];
    const int tid = threadIdx.x;
    const int l   = tid & 63;
    const int w   = tid >> 6;        // wave 0..3
    const int bid = blockIdx.x;
    const int mt  = bid >> 2;
    const int kb  = (bid >> 1) & 1;  // K-half
    const int eh  = bid & 1;         // expert half
    const int m0  = mt * 32;
    const int etile = eh * 4 + w;

#define XA_OFF(buf, lvl, ks) ((((buf) * 2 + (lvl)) * 8 + (ks)) * 1024)

    // staging: thread (w,l) stages ks-slots w and w+4 (64 floats apart)
    const float* Xs_base = X + (size_t)(m0 + (l & 31)) * H
                             + kb * 2048 + w * 16 + 8 * (l >> 5);
    const char* bp = ws + (size_t)etile * 524288 + (size_t)kb * 262144
                        + (size_t)l * 16;

    f32x16 acc_hi, acc_rest, tot;
#pragma unroll
    for (int r = 0; r < 16; ++r) { acc_hi[r] = 0.f; acc_rest[r] = 0.f; tot[r] = 0.f; }

    f32x4 x0a, x0b, x1a, x1b;        // single prefetch set (slots w, w+4)
    union BF { int4 q; f16x8 v; };
    BF rb[8][2];                     // 8-deep ring x 2 levels = 64 VGPR

#define XISSUE(s)                                                          \
    {   const float* p_ = Xs_base + (size_t)(s) * 128;                     \
        x0a = __builtin_nontemporal_load((const f32x4*)p_);                \
        x0b = __builtin_nontemporal_load((const f32x4*)(p_ + 4));          \
        x1a = __builtin_nontemporal_load((const f32x4*)(p_ + 64));         \
        x1b = __builtin_nontemporal_load((const f32x4*)(p_ + 68)); }

#define SPLIT8(r0, r1, d1, d2)                                             \
    {   _Pragma("unroll")                                                  \
        for (int j = 0; j < 8; ++j) {                                      \
            const float x_ = (j < 4) ? r0[j] : r1[j - 4];                  \
            const _Float16 h1_ = (_Float16)x_;                             \
            d1.h[j] = h1_;                                                 \
            d2.h[j] = (_Float16)(x_ - (float)h1_);                         \
        } }

#define XWRITE(buf)                                                        \
    {   union { int4 q; _Float16 h[8]; } w1_, w2_, w3_, w4_;               \
        SPLIT8(x0a, x0b, w1_, w2_)                                         \
        SPLIT8(x1a, x1b, w3_, w4_)                                         \
        *(int4*)(SM + XA_OFF(buf, 0, w)     + l * 16) = w1_.q;             \
        *(int4*)(SM + XA_OFF(buf, 1, w)     + l * 16) = w2_.q;             \
        *(int4*)(SM + XA_OFF(buf, 0, w + 4) + l * 16) = w3_.q;             \
        *(int4*)(SM + XA_OFF(buf, 1, w + 4) + l * 16) = w4_.q; }

#define SLICE_BARRIER()                                                    \
    { asm volatile("s_waitcnt lgkmcnt(0)" ::: "memory");                   \
      __builtin_amdgcn_s_barrier();                                        \
      asm volatile("" ::: "memory"); }

#define STEPS(buf, slice)                                                  \
    {   const int kb8 = (slice) * 8;                                       \
        _Pragma("unroll")                                                  \
        for (int i = 0; i < 8; ++i) {                                      \
            union { int4 q; f16x8 v; } a1, a2;                             \
            a1.q = *(const int4*)(SM + XA_OFF(buf, 0, i) + l * 16);        \
            a2.q = *(const int4*)(SM + XA_OFF(buf, 1, i) + l * 16);        \
            __builtin_amdgcn_s_setprio(1);                                 \
            acc_hi = __builtin_amdgcn_mfma_f32_32x32x16_f16(               \
                a1.v, rb[i][0].v, acc_hi, 0, 0, 0);                        \
            acc_rest = __builtin_amdgcn_mfma_f32_32x32x16_f16(             \
                a1.v, rb[i][1].v, acc_rest, 0, 0, 0);                      \
            acc_rest = __builtin_amdgcn_mfma_f32_32x32x16_f16(             \
                a2.v, rb[i][0].v, acc_rest, 0, 0, 0);                      \
            __builtin_amdgcn_s_setprio(0);                                 \
            const int kn = kb8 + i + 8;  /* 8-step lookahead; tail        */\
            rb[i][0].q = *(const int4*)(bp + (size_t)kn * 2048);           \
            rb[i][1].q = *(const int4*)(bp + (size_t)kn * 2048 + 1024);    \
        }                                                                  \
        _Pragma("unroll")                                                  \
        for (int r = 0; r < 16; ++r) { tot[r] += acc_hi[r]; acc_hi[r] = 0.f; } }

    // prologue: slice 0 staged, slice 1 issued, ring primed with k-steps 0..7
    XISSUE(0)
    XWRITE(0)
    __syncthreads();
    XISSUE(1)
#pragma unroll
    for (int i = 0; i < 8; ++i) {
        rb[i][0].q = *(const int4*)(bp + (size_t)i * 2048);
        rb[i][1].q = *(const int4*)(bp + (size_t)i * 2048 + 1024);
    }

    int cur = 0;
    for (int s = 0; s < 16; ++s) {
        STEPS(cur, s)
        if (s + 1 < 16) {
            XWRITE(cur ^ 1)          // counted vmcnt wait on x regs only
            SLICE_BARRIER()
            if (s + 2 < 16) XISSUE(s + 2)
            cur ^= 1;
        }
    }
#undef XISSUE
#undef SPLIT8
#undef XWRITE
#undef SLICE_BARRIER
#undef STEPS

    // nontemporal fp32 partial store: block chunk = 16KB,
    // idx = ((w*64 + l)*16 + r)   (etile-local w)
    float* pp = (float*)(ws + PART_OFF) + (size_t)bid * 4096
              + (size_t)(w * 64 + l) * 16;
    union { f32x16 v; f32x4 c[4]; } res;
#pragma unroll
    for (int r = 0; r < 16; ++r) res.v[r] = tot[r] + acc_rest[r];
#pragma unroll
    for (int j = 0; j < 4; ++j)
        __builtin_nontemporal_store(res.c[j], (f32x4*)pp + j);
}

// ============================================================================
// Kernel B (v9): 512 blocks x 256 thr, 32 tokens each. Combine the two
// K-half partial chunks per expert-half (fp32 add, deterministic),
// sigmoid+bias into swizzled SC, then the proven gating.
// Chunks for mt: c = kb*2 + eh at PART_OFF + (mt*4 + c)*16KB.
// ============================================================================
__global__ __launch_bounds__(256) void moe_gate_v9(
    const char* __restrict__ ws, const float* __restrict__ bias,
    float* __restrict__ out, int T)
{
    __shared__ float SC[NEXP * 32];   // 32 KB
    const int tid = threadIdx.x;
    const int mt  = blockIdx.x;
    const int m0  = mt * 32;
    const float* pb = (const float*)(ws + PART_OFF) + (size_t)(mt * 4) * 4096;

#pragma unroll 8
    for (int j = 0; j < 32; ++j) {
        const int i  = tid + 256 * j;        // 0..8191
        const int r  = i & 15;
        const int l  = (i >> 4) & 63;
        const int eg = i >> 10;              // global etile 0..7
        const int eh = eg >> 2;              // expert half
        const int wl = eg & 3;               // etile-local wave
        const int idx = (wl * 64 + l) * 16 + r;
        const float v0 = pb[(size_t)(0 + eh) * 4096 + idx];   // kb=0
        const float v1 = pb[(size_t)(2 + eh) * 4096 + idx];   // kb=1
        const int e  = eg * 32 + (l & 31);
        const int ti = (r & 3) + 8 * (r >> 2) + 4 * (l >> 5);
        const float logit = (v0 + v1) * INV_WSCALE;
        const float sv = 1.0f / (1.0f + expf(-logit));
        SC[e * 32 + (ti ^ (e & 31))] = sv + bias[e];
    }
    __syncthreads();

    if (tid < 32) {
        const int t = tid;
        float gs[NGROUP];
#pragma unroll
        for (int g = 0; g < NGROUP; ++g) {
            float m1 = -1e30f, m2 = -1e30f;
            for (int j = 0; j < 32; ++j) {
                const int e = g * 32 + j;
                const float v = SC[e * 32 + (t ^ (e & 31))];
                if (v > m1) { m2 = m1; m1 = v; }
                else if (v > m2) { m2 = v; }
            }
            gs[g] = m1 + m2;
        }
        unsigned gmask = 0;
        for (int r = 0; r < TOPKG; ++r) {
            int bi = 0; float bv = -1e30f;
#pragma unroll
            for (int g = 0; g < NGROUP; ++g)
                if (!((gmask >> g) & 1u) && gs[g] > bv) { bv = gs[g]; bi = g; }
            gmask |= (1u << bi);
        }
        int glist[TOPKG], ng = 0;
#pragma unroll
        for (int g = 0; g < NGROUP; ++g)
            if ((gmask >> g) & 1u) glist[ng++] = g;
        int eidx[TOPK]; float sval[TOPK];
        unsigned cmask[TOPKG] = {0u, 0u, 0u, 0u};
        float wsum = 0.f;
        for (int r = 0; r < TOPK; ++r) {
            float bv = -1e30f; int bgi = 0, bj = 0;
            for (int gi = 0; gi < TOPKG; ++gi) {
                const int g = glist[gi];
                for (int j = 0; j < 32; ++j) {
                    if ((cmask[gi] >> j) & 1u) continue;
                    const int e = g * 32 + j;
                    const float v = SC[e * 32 + (t ^ (e & 31))];
                    if (v > bv) { bv = v; bgi = gi; bj = j; }
                }
            }
            cmask[bgi] |= (1u << bj);
            const int e = glist[bgi] * 32 + bj;
            eidx[r] = e;
            const float sig = bv - bias[e];
            sval[r] = sig; wsum += sig;
        }
        const float scale = ROUTED_SCALING / (wsum + 1e-20f);
        const size_t gt = (size_t)(m0 + t);
#pragma unroll
        for (int r = 0; r < TOPK; ++r) {
            out[gt * TOPK + r] = (float)eidx[r];
            out[(size_t)T * TOPK + gt * TOPK + r] = sval[r] * scale;
        }
    }
}

// ============================================================================
// Fallback (round-3 fp32 kernel, verified) if ws < WS_NEED.
// ============================================================================
#define BMF 32
#define BKF 32
#define WS_STRIDE 388
#define XS_STRIDE 36
#define WS_FLOATS (BKF * WS_STRIDE)
#define SMEM_FLOATS (WS_FLOATS + BKF * XS_STRIDE)

__global__ __launch_bounds__(256, 2) void moe_gate_f32(
    const float* __restrict__ X, const float* __restrict__ W,
    const float* __restrict__ bias, float* __restrict__ out, int T)
{
    __shared__ float smem[SMEM_FLOATS];
    float* Ws = smem;
    float* Xs = smem + WS_FLOATS;
    float* SC = smem;
    const int tid = threadIdx.x;
    const int tq  = tid >> 5;
    const int tx  = tid & 31;
    const int m0  = blockIdx.x * BMF;
    const int q  = tid & 7;
    const int sx = tid >> 3;
    float acc[4][8];
#pragma unroll
    for (int r = 0; r < 4; ++r)
#pragma unroll
        for (int c = 0; c < 8; ++c) acc[r][c] = 0.f;
    float4 xr, wr[8];
    const float* Xbase = X + (size_t)(m0 + sx) * H + 4 * q;
    const float* Wbase = W + (size_t)sx * H + 4 * q;
    auto loadTile = [&](int k0) {
        xr = *(const float4*)(Xbase + k0);
#pragma unroll
        for (int i = 0; i < 8; ++i)
            wr[i] = *(const float4*)(Wbase + (size_t)(32 * i) * H + k0);
    };
    auto storeTile = [&]() {
        Xs[(4 * q + 0) * XS_STRIDE + sx] = xr.x;
        Xs[(4 * q + 1) * XS_STRIDE + sx] = xr.y;
        Xs[(4 * q + 2) * XS_STRIDE + sx] = xr.z;
        Xs[(4 * q + 3) * XS_STRIDE + sx] = xr.w;
#pragma unroll
        for (int i = 0; i < 8; ++i) {
            const int e = sx + 32 * i;
            const int col = 12 * (e >> 3) + (e & 7);
            Ws[(4 * q + 0) * WS_STRIDE + col] = wr[i].x;
            Ws[(4 * q + 1) * WS_STRIDE + col] = wr[i].y;
            Ws[(4 * q + 2) * WS_STRIDE + col] = wr[i].z;
            Ws[(4 * q + 3) * WS_STRIDE + col] = wr[i].w;
        }
    };
    loadTile(0);
    for (int k0 = 0; k0 < H; k0 += BKF) {
        storeTile();
        __syncthreads();
        if (k0 + BKF < H) loadTile(k0 + BKF);
#pragma unroll 8
        for (int kk = 0; kk < BKF; ++kk) {
            float a[4], b[8];
            *(float4*)&a[0] = *(const float4*)&Xs[kk * XS_STRIDE + 4 * tq];
            *(float4*)&b[0] = *(const float4*)&Ws[kk * WS_STRIDE + 12 * tx];
            *(float4*)&b[4] = *(const float4*)&Ws[kk * WS_STRIDE + 12 * tx + 4];
#pragma unroll
            for (int r = 0; r < 4; ++r)
#pragma unroll
                for (int c = 0; c < 8; ++c)
                    acc[r][c] = fmaf(a[r], b[c], acc[r][c]);
        }
        __syncthreads();
    }
#pragma unroll
    for (int c = 0; c < 8; ++c) {
        const int e = 8 * tx + c;
        const float be = bias[e];
#pragma unroll
        for (int r = 0; r < 4; ++r) {
            const int t = 4 * tq + r;
            const float s = 1.0f / (1.0f + expf(-acc[r][c]));
            SC[e * 32 + (t ^ tx)] = s + be;
        }
    }
    __syncthreads();
    if (tid < BMF) {
        const int t = tid;
        float gs[NGROUP];
#pragma unroll
        for (int g = 0; g < NGROUP; ++g) {
            float m1 = -1e30f, m2 = -1e30f;
            for (int j = 0; j < 32; ++j) {
                const int e = g * 32 + j;
                const float v = SC[e * 32 + (t ^ (e >> 3))];
                if (v > m1) { m2 = m1; m1 = v; }
                else if (v > m2) { m2 = v; }
            }
            gs[g] = m1 + m2;
        }
        unsigned gmask = 0;
        for (int r = 0; r < TOPKG; ++r) {
            int bi = 0; float bv = -1e30f;
#pragma unroll
            for (int g = 0; g < NGROUP; ++g)
                if (!((gmask >> g) & 1u) && gs[g] > bv) { bv = gs[g]; bi = g; }
            gmask |= (1u << bi);
        }
        int glist[TOPKG], ng = 0;
#pragma unroll
        for (int g = 0; g < NGROUP; ++g)
            if ((gmask >> g) & 1u) glist[ng++] = g;
        int eidx[TOPK]; float sval[TOPK];
        unsigned cmask[TOPKG] = {0u, 0u, 0u, 0u};
        float wsum = 0.f;
        for (int r = 0; r < TOPK; ++r) {
            float bv = -1e30f; int bgi = 0, bj = 0;
            for (int gi = 0; gi < TOPKG; ++gi) {
                const int g = glist[gi];
                for (int j = 0; j < 32; ++j) {
                    if ((cmask[gi] >> j) & 1u) continue;
                    const int e = g * 32 + j;
                    const float v = SC[e * 32 + (t ^ (e >> 3))];
                    if (v > bv) { bv = v; bgi = gi; bj = j; }
                }
            }
            cmask[bgi] |= (1u << bj);
            const int e = glist[bgi] * 32 + bj;
            eidx[r] = e;
            const float sig = bv - bias[e];
            sval[r] = sig; wsum += sig;
        }
        const float scale = ROUTED_SCALING / (wsum + 1e-20f);
        const size_t gt = (size_t)(m0 + t);
#pragma unroll
        for (int r = 0; r < TOPK; ++r) {
            out[gt * TOPK + r] = (float)eidx[r];
            out[(size_t)T * TOPK + gt * TOPK + r] = sval[r] * scale;
        }
    }
}

extern "C" void kernel_launch(void* const* d_in, const int* in_sizes, int n_in,
                              void* d_out, int out_size, void* d_ws, size_t ws_size,
                              hipStream_t stream) {
    const float* X = (const float*)d_in[0];
    const float* W = (const float*)d_in[1];
    const float* B = (const float*)d_in[2];
    float* out = (float*)d_out;
    const int T = in_sizes[0] / H;            // 16384
    if (ws_size >= WS_NEED) {
        wsplit_kernel<<<512, 256, 0, stream>>>(W, (char*)d_ws);
        moe_partial_v9<<<4 * (T / 32), 256, 0, stream>>>(X, (char*)d_ws, T);
        moe_gate_v9<<<T / 32, 256, 0, stream>>>((const char*)d_ws, B, out, T);
    } else {
        moe_gate_f32<<<T / 32, 256, 0, stream>>>(X, W, B, out, T);
    }
}

// Round 16
// 258.415 us; speedup vs baseline: 1.2860x; 1.2860x over previous
//
#include <hip/hip_runtime.h>
#include <hip/hip_bf16.h>

#define H 4096
#define NEXP 256
#define TOPK 8
#define NGROUP 8
#define TOPKG 4
#define ROUTED_SCALING 2.5f
#define WSCALE 1024.0f
#define INV_WSCALE (1.0f / 1024.0f)

#define PART_OFF ((size_t)4 * 1024 * 1024)
#define WS_NEED  (PART_OFF + (size_t)1024 * 32768)   // 4MB wfrags + 32MB partials

typedef __attribute__((ext_vector_type(8)))  _Float16 f16x8;
typedef __attribute__((ext_vector_type(16))) float    f32x16;
typedef __attribute__((ext_vector_type(4)))  float    f32x4;

// ============================================================================
// Pre-kernel (v10, coalesced): split W*1024 into 2 fp16 levels, fragment
// order, levels interleaved: etile*524288 + (ks*2+lvl)*1024 + l*16.
// Thread = 8 contiguous k of one expert -> reads fully coalesced (2KB/wave).
// Contract: lane l holds W[etile*32+(l&31)][16ks + 8*(l>>5) + j], j=0..7.
//   thread (expert, k0): ks=k0>>4, half=(k0>>3)&1, l=(expert&31)|(half<<5).
// ============================================================================
__global__ __launch_bounds__(256) void wsplit_v10(
    const float* __restrict__ W, char* __restrict__ ws)
{
    const int t  = blockIdx.x * 256 + threadIdx.x;   // 0..131071
    const int expert = t >> 9;
    const int kq = t & 511;
    const int k0 = kq * 8;
    const float* src = W + (size_t)expert * H + k0;
    float xf[8];
    *(float4*)&xf[0] = *(const float4*)(src);
    *(float4*)&xf[4] = *(const float4*)(src + 4);
    union { _Float16 h[8]; int4 q; } o1, o2;
#pragma unroll
    for (int j = 0; j < 8; ++j) {
        const float x = xf[j] * WSCALE;
        const _Float16 h1 = (_Float16)x;
        o1.h[j] = h1;
        o2.h[j] = (_Float16)(x - (float)h1);
    }
    const int etile = expert >> 5;
    const int ks    = k0 >> 4;
    const int l     = (expert & 31) | (((k0 >> 3) & 1) << 5);
    const size_t off = (size_t)etile * 524288
                     + (size_t)(ks * 2) * 1024 + (size_t)l * 16;
    *(int4*)(ws + off)        = o1.q;
    *(int4*)(ws + off + 1024) = o2.q;
}

// ============================================================================
// Kernel A: v6 VERBATIM (round-12 champion, 175us measured).
// 1024 blocks x 512 thr (2 blocks/CU, 16 waves/CU).
// Block (mt=bid>>1, kb=bid&1): 32 tokens x 256 experts x half-K; kb constant
// per XCD -> per-XCD B set 2MB. B-BW-bound at ~11.4 TB/s effective L2/L3.
// Numerics (proven r5..r12): x1w1 -> acc_hi drained to fp32 tot per slice;
// x1w2+x2w1 chained in acc_rest (2^-11 scale).
// ============================================================================
__global__ __launch_bounds__(512, 4) void moe_partial_v6(
    const float* __restrict__ X, char* ws, int T)
{
    __shared__ __align__(16) char SM[32768];
    const int tid = threadIdx.x;
    const int l   = tid & 63;
    const int eg  = tid >> 6;
    const int sks = tid >> 6;
    const int bid = blockIdx.x;
    const int kb  = bid & 1;
    const int mt  = bid >> 1;
    const int m0  = mt * 32;

#define XA_OFF(buf, lvl, ks) ((((buf) * 2 + (lvl)) * 8 + (ks)) * 1024)

    const float* Xs_base = X + (size_t)(m0 + (l & 31)) * H
                             + kb * 2048 + sks * 16 + 8 * (l >> 5);
    const char*  bp      = ws + (size_t)eg * 524288
                              + (size_t)(kb * 128) * 2048 + (size_t)l * 16;

    f32x16 acc_hi, acc_rest, tot;
#pragma unroll
    for (int r = 0; r < 16; ++r) { acc_hi[r] = 0.f; acc_rest[r] = 0.f; tot[r] = 0.f; }

    f32x4 xa0, xa1, xb0, xb1;
    union BF { int4 q; f16x8 v; };
    BF rb[4][2];

#define XISSUE_A(s)                                                        \
    {   const float* p_ = Xs_base + (size_t)(s) * 128;                     \
        xa0 = __builtin_nontemporal_load((const f32x4*)p_);                \
        xa1 = __builtin_nontemporal_load((const f32x4*)(p_ + 4)); }
#define XISSUE_B(s)                                                        \
    {   const float* p_ = Xs_base + (size_t)(s) * 128;                     \
        xb0 = __builtin_nontemporal_load((const f32x4*)p_);                \
        xb1 = __builtin_nontemporal_load((const f32x4*)(p_ + 4)); }

#define XWRITE_IMPL(buf, r0, r1)                                           \
    {   union { int4 q; _Float16 h[8]; } w1_, w2_;                         \
        _Pragma("unroll")                                                  \
        for (int j = 0; j < 8; ++j) {                                      \
            const float x_ = (j < 4) ? r0[j] : r1[j - 4];                  \
            const _Float16 h1_ = (_Float16)x_;                             \
            w1_.h[j] = h1_;                                                \
            w2_.h[j] = (_Float16)(x_ - (float)h1_);                        \
        }                                                                  \
        *(int4*)(SM + XA_OFF(buf, 0, sks) + l * 16) = w1_.q;               \
        *(int4*)(SM + XA_OFF(buf, 1, sks) + l * 16) = w2_.q; }
#define XWRITE_A(buf) XWRITE_IMPL(buf, xa0, xa1)
#define XWRITE_B(buf) XWRITE_IMPL(buf, xb0, xb1)

#define SLICE_BARRIER()                                                    \
    { asm volatile("s_waitcnt lgkmcnt(0)" ::: "memory");                   \
      __builtin_amdgcn_s_barrier();                                        \
      asm volatile("" ::: "memory"); }

#define STEPS(buf, slice)                                                  \
    {   const int kb8 = (slice) * 8;                                       \
        _Pragma("unroll")                                                  \
        for (int i = 0; i < 8; ++i) {                                      \
            union { int4 q; f16x8 v; } a1, a2;                             \
            a1.q = *(const int4*)(SM + XA_OFF(buf, 0, i) + l * 16);        \
            a2.q = *(const int4*)(SM + XA_OFF(buf, 1, i) + l * 16);        \
            acc_hi = __builtin_amdgcn_mfma_f32_32x32x16_f16(               \
                a1.v, rb[i & 3][0].v, acc_hi, 0, 0, 0);                    \
            acc_rest = __builtin_amdgcn_mfma_f32_32x32x16_f16(             \
                a1.v, rb[i & 3][1].v, acc_rest, 0, 0, 0);                  \
            acc_rest = __builtin_amdgcn_mfma_f32_32x32x16_f16(             \
                a2.v, rb[i & 3][0].v, acc_rest, 0, 0, 0);                  \
            const int kn = kb8 + i + 4;   /* tail over-read stays in ws */ \
            rb[i & 3][0].q = *(const int4*)(bp + (size_t)kn * 2048);       \
            rb[i & 3][1].q = *(const int4*)(bp + (size_t)kn * 2048 + 1024);\
        }                                                                  \
        _Pragma("unroll")                                                  \
        for (int r = 0; r < 16; ++r) { tot[r] += acc_hi[r]; acc_hi[r] = 0.f; } }

    XISSUE_A(0)
    XWRITE_A(0)
    __syncthreads();
    XISSUE_A(1)
    XISSUE_B(2)
#pragma unroll
    for (int i = 0; i < 4; ++i) {
        rb[i][0].q = *(const int4*)(bp + (size_t)i * 2048);
        rb[i][1].q = *(const int4*)(bp + (size_t)i * 2048 + 1024);
    }

    for (int s = 0; s < 16; s += 2) {
        STEPS(0, s)
        XWRITE_A(1)
        SLICE_BARRIER()
        if (s + 3 < 16) XISSUE_A(s + 3)
        STEPS(1, s + 1)
        if (s + 2 < 16) {
            XWRITE_B(0)
            SLICE_BARRIER()
            if (s + 4 < 16) XISSUE_B(s + 4)
        }
    }
#undef XISSUE_A
#undef XISSUE_B
#undef XWRITE_IMPL
#undef XWRITE_A
#undef XWRITE_B
#undef SLICE_BARRIER
#undef STEPS

    // nontemporal fp32 partial store: chunk idx = (eg*64 + l)*16 + r
    float* pp = (float*)(ws + PART_OFF) + (size_t)bid * 8192
              + (size_t)(eg * 64 + l) * 16;
    union { f32x16 v; f32x4 c[4]; } res;
#pragma unroll
    for (int r = 0; r < 16; ++r) res.v[r] = tot[r] + acc_rest[r];
#pragma unroll
    for (int j = 0; j < 4; ++j)
        __builtin_nontemporal_store(res.c[j], (f32x4*)pp + j);
}

// ============================================================================
// Kernel B (v10): 256 blocks x 256 thr, 64 tokens/block (2 mt-tiles).
// f32x4-vectorized partial combine (layout is r-contiguous), sigmoid+bias
// into swizzled SC[256][64], then the proven gating (threads 0..63).
// ============================================================================
__global__ __launch_bounds__(256) void moe_gate_v10(
    const char* __restrict__ ws, const float* __restrict__ bias,
    float* __restrict__ out, int T)
{
    __shared__ float SC[NEXP * 64];   // 64 KB
    const int tid = threadIdx.x;
    const int m0  = blockIdx.x * 64;
    const float* pbase = (const float*)(ws + PART_OFF);

    // token halves h=0,1 -> mt = 2*blockIdx + h; chunks mt*2 (kb=0), mt*2+1
#pragma unroll
    for (int h = 0; h < 2; ++h) {
        const int mt = 2 * blockIdx.x + h;
        const float* p0 = pbase + (size_t)(mt * 2) * 8192;
        const float* p1 = p0 + 8192;
#pragma unroll
        for (int jv = 0; jv < 8; ++jv) {
            const int v  = tid + 256 * jv;       // 0..2047 (f32x4 index)
            const int r0 = (v & 3) * 4;
            const int l  = (v >> 2) & 63;
            const int eg = v >> 8;
            const int idx = (eg * 64 + l) * 16 + r0;
            const f32x4 a = *(const f32x4*)(p0 + idx);
            const f32x4 b = *(const f32x4*)(p1 + idx);
            const int e  = eg * 32 + (l & 31);
            const float be = bias[e];
#pragma unroll
            for (int jj = 0; jj < 4; ++jj) {
                const int r  = r0 + jj;
                const int ti = h * 32 + (r & 3) + 8 * (r >> 2) + 4 * (l >> 5);
                const float logit = (a[jj] + b[jj]) * INV_WSCALE;
                const float sv = 1.0f / (1.0f + expf(-logit));
                SC[e * 64 + (ti ^ (e & 31))] = sv + be;
            }
        }
    }
    __syncthreads();

    if (tid < 64) {
        const int t = tid;
        float gs[NGROUP];
#pragma unroll
        for (int g = 0; g < NGROUP; ++g) {
            float m1 = -1e30f, m2 = -1e30f;
            for (int j = 0; j < 32; ++j) {
                const int e = g * 32 + j;
                const float v = SC[e * 64 + (t ^ (e & 31))];
                if (v > m1) { m2 = m1; m1 = v; }
                else if (v > m2) { m2 = v; }
            }
            gs[g] = m1 + m2;
        }
        unsigned gmask = 0;
        for (int r = 0; r < TOPKG; ++r) {
            int bi = 0; float bv = -1e30f;
#pragma unroll
            for (int g = 0; g < NGROUP; ++g)
                if (!((gmask >> g) & 1u) && gs[g] > bv) { bv = gs[g]; bi = g; }
            gmask |= (1u << bi);
        }
        int glist[TOPKG], ng = 0;
#pragma unroll
        for (int g = 0; g < NGROUP; ++g)
            if ((gmask >> g) & 1u) glist[ng++] = g;
        int eidx[TOPK]; float sval[TOPK];
        unsigned cmask[TOPKG] = {0u, 0u, 0u, 0u};
        float wsum = 0.f;
        for (int r = 0; r < TOPK; ++r) {
            float bv = -1e30f; int bgi = 0, bj = 0;
            for (int gi = 0; gi < TOPKG; ++gi) {
                const int g = glist[gi];
                for (int j = 0; j < 32; ++j) {
                    if ((cmask[gi] >> j) & 1u) continue;
                    const int e = g * 32 + j;
                    const float v = SC[e * 64 + (t ^ (e & 31))];
                    if (v > bv) { bv = v; bgi = gi; bj = j; }
                }
            }
            cmask[bgi] |= (1u << bj);
            const int e = glist[bgi] * 32 + bj;
            eidx[r] = e;
            const float sig = bv - bias[e];
            sval[r] = sig; wsum += sig;
        }
        const float scale = ROUTED_SCALING / (wsum + 1e-20f);
        const size_t gt = (size_t)(m0 + t);
#pragma unroll
        for (int r = 0; r < TOPK; ++r) {
            out[gt * TOPK + r] = (float)eidx[r];
            out[(size_t)T * TOPK + gt * TOPK + r] = sval[r] * scale;
        }
    }
}

// ============================================================================
// Fallback (round-3 fp32 kernel, verified) if ws < WS_NEED.
// ============================================================================
#define BMF 32
#define BKF 32
#define WS_STRIDE 388
#define XS_STRIDE 36
#define WS_FLOATS (BKF * WS_STRIDE)
#define SMEM_FLOATS (WS_FLOATS + BKF * XS_STRIDE)

__global__ __launch_bounds__(256, 2) void moe_gate_f32(
    const float* __restrict__ X, const float* __restrict__ W,
    const float* __restrict__ bias, float* __restrict__ out, int T)
{
    __shared__ float smem[SMEM_FLOATS];
    float* Ws = smem;
    float* Xs = smem + WS_FLOATS;
    float* SC = smem;
    const int tid = threadIdx.x;
    const int tq  = tid >> 5;
    const int tx  = tid & 31;
    const int m0  = blockIdx.x * BMF;
    const int q  = tid & 7;
    const int sx = tid >> 3;
    float acc[4][8];
#pragma unroll
    for (int r = 0; r < 4; ++r)
#pragma unroll
        for (int c = 0; c < 8; ++c) acc[r][c] = 0.f;
    float4 xr, wr[8];
    const float* Xbase = X + (size_t)(m0 + sx) * H + 4 * q;
    const float* Wbase = W + (size_t)sx * H + 4 * q;
    auto loadTile = [&](int k0) {
        xr = *(const float4*)(Xbase + k0);
#pragma unroll
        for (int i = 0; i < 8; ++i)
            wr[i] = *(const float4*)(Wbase + (size_t)(32 * i) * H + k0);
    };
    auto storeTile = [&]() {
        Xs[(4 * q + 0) * XS_STRIDE + sx] = xr.x;
        Xs[(4 * q + 1) * XS_STRIDE + sx] = xr.y;
        Xs[(4 * q + 2) * XS_STRIDE + sx] = xr.z;
        Xs[(4 * q + 3) * XS_STRIDE + sx] = xr.w;
#pragma unroll
        for (int i = 0; i < 8; ++i) {
            const int e = sx + 32 * i;
            const int col = 12 * (e >> 3) + (e & 7);
            Ws[(4 * q + 0) * WS_STRIDE + col] = wr[i].x;
            Ws[(4 * q + 1) * WS_STRIDE + col] = wr[i].y;
            Ws[(4 * q + 2) * WS_STRIDE + col] = wr[i].z;
            Ws[(4 * q + 3) * WS_STRIDE + col] = wr[i].w;
        }
    };
    loadTile(0);
    for (int k0 = 0; k0 < H; k0 += BKF) {
        storeTile();
        __syncthreads();
        if (k0 + BKF < H) loadTile(k0 + BKF);
#pragma unroll 8
        for (int kk = 0; kk < BKF; ++kk) {
            float a[4], b[8];
            *(float4*)&a[0] = *(const float4*)&Xs[kk * XS_STRIDE + 4 * tq];
            *(float4*)&b[0] = *(const float4*)&Ws[kk * WS_STRIDE + 12 * tx];
            *(float4*)&b[4] = *(const float4*)&Ws[kk * WS_STRIDE + 12 * tx + 4];
#pragma unroll
            for (int r = 0; r < 4; ++r)
#pragma unroll
                for (int c = 0; c < 8; ++c)
                    acc[r][c] = fmaf(a[r], b[c], acc[r][c]);
        }
        __syncthreads();
    }
#pragma unroll
    for (int c = 0; c < 8; ++c) {
        const int e = 8 * tx + c;
        const float be = bias[e];
#pragma unroll
        for (int r = 0; r < 4; ++r) {
            const int t = 4 * tq + r;
            const float s = 1.0f / (1.0f + expf(-acc[r][c]));
            SC[e * 32 + (t ^ tx)] = s + be;
        }
    }
    __syncthreads();
    if (tid < BMF) {
        const int t = tid;
        float gs[NGROUP];
#pragma unroll
        for (int g = 0; g < NGROUP; ++g) {
            float m1 = -1e30f, m2 = -1e30f;
            for (int j = 0; j < 32; ++j) {
                const int e = g * 32 + j;
                const float v = SC[e * 32 + (t ^ (e >> 3))];
                if (v > m1) { m2 = m1; m1 = v; }
                else if (v > m2) { m2 = v; }
            }
            gs[g] = m1 + m2;
        }
        unsigned gmask = 0;
        for (int r = 0; r < TOPKG; ++r) {
            int bi = 0; float bv = -1e30f;
#pragma unroll
            for (int g = 0; g < NGROUP; ++g)
                if (!((gmask >> g) & 1u) && gs[g] > bv) { bv = gs[g]; bi = g; }
            gmask |= (1u << bi);
        }
        int glist[TOPKG], ng = 0;
#pragma unroll
        for (int g = 0; g < NGROUP; ++g)
            if ((gmask >> g) & 1u) glist[ng++] = g;
        int eidx[TOPK]; float sval[TOPK];
        unsigned cmask[TOPKG] = {0u, 0u, 0u, 0u};
        float wsum = 0.f;
        for (int r = 0; r < TOPK; ++r) {
            float bv = -1e30f; int bgi = 0, bj = 0;
            for (int gi = 0; gi < TOPKG; ++gi) {
                const int g = glist[gi];
                for (int j = 0; j < 32; ++j) {
                    if ((cmask[gi] >> j) & 1u) continue;
                    const int e = g * 32 + j;
                    const float v = SC[e * 32 + (t ^ (e >> 3))];
                    if (v > bv) { bv = v; bgi = gi; bj = j; }
                }
            }
            cmask[bgi] |= (1u << bj);
            const int e = glist[bgi] * 32 + bj;
            eidx[r] = e;
            const float sig = bv - bias[e];
            sval[r] = sig; wsum += sig;
        }
        const float scale = ROUTED_SCALING / (wsum + 1e-20f);
        const size_t gt = (size_t)(m0 + t);
#pragma unroll
        for (int r = 0; r < TOPK; ++r) {
            out[gt * TOPK + r] = (float)eidx[r];
            out[(size_t)T * TOPK + gt * TOPK + r] = sval[r] * scale;
        }
    }
}

extern "C" void kernel_launch(void* const* d_in, const int* in_sizes, int n_in,
                              void* d_out, int out_size, void* d_ws, size_t ws_size,
                              hipStream_t stream) {
    const float* X = (const float*)d_in[0];
    const float* W = (const float*)d_in[1];
    const float* B = (const float*)d_in[2];
    float* out = (float*)d_out;
    const int T = in_sizes[0] / H;            // 16384
    if (ws_size >= WS_NEED) {
        wsplit_v10<<<512, 256, 0, stream>>>(W, (char*)d_ws);
        moe_partial_v6<<<2 * (T / 32), 512, 0, stream>>>(X, (char*)d_ws, T);
        moe_gate_v10<<<T / 64, 256, 0, stream>>>((const char*)d_ws, B, out, T);
    } else {
        moe_gate_f32<<<T / 32, 256, 0, stream>>>(X, W, B, out, T);
    }
}